// Round 2
// baseline (2571.803 us; speedup 1.0000x reference)
//
#include <hip/hip_runtime.h>

// Persistent per-matrix Newton-Schulz sqrtm. B=256, D=256, iterN=5.
// Round 7: collapse setup + 12 batched-GEMM dispatches into ONE kernel.
// The chain is per-matrix (no cross-matrix deps), so grid=256 and one
// 512-thread block owns one matrix for the whole chain; steps separated by
// __threadfence() (L1 invalidate for same-block global RAW) + __syncthreads().
// Removes 12 launch ramps/drains and the 2x A/B HBM refetch of the 4-tile
// decomposition (each step now reads each 256KB operand exactly once).
//
// Storage: fp32 emulated as 2-term bf16 planes (hi+lo), product via 3 MFMA:
//   A@B ~= Ah@Bh + Al@Bh + Ah@Bl
// All iterates are symmetric polynomials in A => C = A@B^T == A@B, so both
// operands are read as [outer][k] rows (no transposition anywhere).
//
// LDS: BK=64 k-tiles, 4 arrays x 32KB = 128KB, staged by global_load_lds
// (linear dest). 3-bit XOR swizzle (slot ^= (row>>1)&7) applied on the
// pre-swizzled GLOBAL source + same XOR on ds_read (rule #21) => 2-way
// (free) bank aliasing at the 128B row stride.
//
// Chain (X = A planes live in d_out, dead before final fp32 overwrite):
//   Z1 = 1.5I - 0.5A
//   3x:  W = A@Z ; T = 1.5W - 0.5(Z@W) ; Z' = T@Z
//   fin: W = A@Z ; T = 1.5W - 0.5(W@Z) ; out = sqrt(normA)*(T@W)

#define DD 256
#define PLN 65536   // shorts per bf16 plane
#define MATN 65536  // floats per fp32 matrix

typedef short s16x8 __attribute__((ext_vector_type(8)));
typedef short s16x4 __attribute__((ext_vector_type(4)));
typedef float f32x4 __attribute__((ext_vector_type(4)));

__device__ __forceinline__ short bf16rtn(float f) {
    unsigned u = __float_as_uint(f);
    u += 0x7FFFu + ((u >> 16) & 1u);   // round-to-nearest-even
    return (short)(u >> 16);
}
__device__ __forceinline__ float bf16tof(short h) {
    return __uint_as_float(((unsigned)(unsigned short)h) << 16);
}
__device__ __forceinline__ void gload16(const short* g, const short* l) {
    __builtin_amdgcn_global_load_lds(
        (const __attribute__((address_space(1))) void*)g,
        (__attribute__((address_space(3))) void*)l, 16, 0, 0);
}

__global__ __launch_bounds__(512, 2) void sqrtm_chain(
    const float* __restrict__ x, float* __restrict__ out,
    short* __restrict__ ws)
{
    __shared__ __align__(16) short sAh[16384];
    __shared__ __align__(16) short sAl[16384];
    __shared__ __align__(16) short sBh[16384];
    __shared__ __align__(16) short sBl[16384];
    __shared__ float red[8];
    __shared__ float sSc[2];

    const int lb = blockIdx.x, tid = threadIdx.x;
    const int wave = tid >> 6, lane = tid & 63;
    const int ln = lane & 15, quad = lane >> 4;
    const int wr = wave & 3, wc = wave >> 2;   // wave tile: rows wr*64, cols wc*128
    const int sw = (ln >> 1) & 7;              // read-side swizzle key

    const float* X = x + (size_t)lb * MATN;
    float* O = out + (size_t)lb * MATN;
    short* Xpl = (short*)O;                    // A planes live in out region
    short* S0 = ws + (size_t)lb * (6 * (size_t)PLN);
    short* S1 = S0 + 2 * PLN;
    short* S2 = S0 + 4 * PLN;

    // ---------------- setup: normA, A planes, Z1 planes ----------------
    {
        float s = 0.f;
#pragma unroll
        for (int i = 0; i < 32; ++i) {
            const float4 v = *(const float4*)(X + ((i * 512 + tid) << 2));
            s += v.x + v.y + v.z + v.w;
        }
#pragma unroll
        for (int o = 32; o; o >>= 1) s += __shfl_down(s, o, 64);
        if (lane == 0) red[wave] = s;
        __syncthreads();
        if (tid == 0) {
            float t = 0.f;
#pragma unroll
            for (int i = 0; i < 8; ++i) t += red[i];
            sSc[0] = 1.f / t;
            sSc[1] = sqrtf(t);
        }
        __syncthreads();
    }
    const float invN = sSc[0];
    const float sqrtN = sSc[1];
    {
        short* Xh = Xpl;  short* Xl = Xpl + PLN;
        short* Zh = S0;   short* Zl = S0 + PLN;
#pragma unroll 4
        for (int i = 0; i < 32; ++i) {
            const int e = (i * 512 + tid) << 2;
            const int r = e >> 8, c = e & 255;
            const float4 v = *(const float4*)(X + e);
            const float a0 = invN * v.x, a1 = invN * v.y,
                        a2 = invN * v.z, a3 = invN * v.w;
            s16x4 xh, xl, zh, zl;
            xh[0] = bf16rtn(a0); xl[0] = bf16rtn(a0 - bf16tof(xh[0]));
            xh[1] = bf16rtn(a1); xl[1] = bf16rtn(a1 - bf16tof(xh[1]));
            xh[2] = bf16rtn(a2); xl[2] = bf16rtn(a2 - bf16tof(xh[2]));
            xh[3] = bf16rtn(a3); xl[3] = bf16rtn(a3 - bf16tof(xh[3]));
            const float z0 = ((r == c + 0) ? 1.5f : 0.f) - 0.5f * a0;
            const float z1 = ((r == c + 1) ? 1.5f : 0.f) - 0.5f * a1;
            const float z2 = ((r == c + 2) ? 1.5f : 0.f) - 0.5f * a2;
            const float z3 = ((r == c + 3) ? 1.5f : 0.f) - 0.5f * a3;
            zh[0] = bf16rtn(z0); zl[0] = bf16rtn(z0 - bf16tof(zh[0]));
            zh[1] = bf16rtn(z1); zl[1] = bf16rtn(z1 - bf16tof(zh[1]));
            zh[2] = bf16rtn(z2); zl[2] = bf16rtn(z2 - bf16tof(zh[2]));
            zh[3] = bf16rtn(z3); zl[3] = bf16rtn(z3 - bf16tof(zh[3]));
            *(s16x4*)(Xh + e) = xh; *(s16x4*)(Xl + e) = xl;
            *(s16x4*)(Zh + e) = zh; *(s16x4*)(Zl + e) = zl;
        }
    }
    __threadfence();
    __syncthreads();

    // staging coords (fixed per thread): waves 0-1 -> Ah, 2-3 -> Al,
    // 4-5 -> Bh, 6-7 -> Bl; 128 threads/array, 16 rows each (stride 16).
    const int arr = tid >> 7;
    const int idx = tid & 127;
    const int r0 = idx >> 3;                   // 0..15
    const int slot = idx & 7;                  // 0..7
    const int gs = slot ^ ((r0 >> 1) & 7);     // pre-swizzled source slot
    short* lbase = (arr == 0) ? sAh : (arr == 1) ? sAl : (arr == 2) ? sBh : sBl;
    short* const myl = lbase + (wave & 1) * 512;   // wave-uniform LDS dest
    const int goff = r0 * DD + gs * 8;

    // step tables: operand/dest slot ids (0,1,2 = ws slots; 3 = A planes)
    const signed char sa_[12] = {3,0,2, 3,1,2, 3,0,2, 3,0,2};
    const signed char sb_[12] = {0,1,0, 1,0,1, 0,1,0, 1,1,0};
    const signed char sc_[12] = {1,2,1, 0,2,0, 1,2,1, 0,2,0};   // sc_[11] unused
    const signed char ax_[12] = {-1,1,-1, -1,0,-1, -1,1,-1, -1,0,-1};
    short* Sl4[4] = {S0, S1, S2, Xpl};

    for (int st = 0; st < 12; ++st) {
        const short* Ap = Sl4[(int)sa_[st]];
        const short* Bp = Sl4[(int)sb_[st]];
        const short* gbase = ((arr < 2) ? Ap : Bp) + (arr & 1) * PLN + goff;

        f32x4 acc[4][8];
#pragma unroll
        for (int i = 0; i < 4; ++i)
#pragma unroll
            for (int j = 0; j < 8; ++j) {
                acc[i][j][0] = 0.f; acc[i][j][1] = 0.f;
                acc[i][j][2] = 0.f; acc[i][j][3] = 0.f;
            }

        for (int kt = 0; kt < DD; kt += 64) {
            __syncthreads();                   // prev LDS reads done
#pragma unroll
            for (int rr = 0; rr < 16; ++rr)
                gload16(gbase + kt + rr * (16 * DD), myl + rr * 1024);
            __syncthreads();                   // vmcnt(0) drain + barrier

#pragma unroll
            for (int kh = 0; kh < 2; ++kh) {
                const int ks8 = kh * 4;
                s16x8 ahf[4], alf[4];
#pragma unroll
                for (int i = 0; i < 4; ++i) {
                    const int ro = (wr * 64 + i * 16 + ln) * 64
                                 + (((ks8 + quad) ^ sw) << 3);
                    ahf[i] = *(const s16x8*)(sAh + ro);
                    alf[i] = *(const s16x8*)(sAl + ro);
                }
#pragma unroll
                for (int j = 0; j < 8; ++j) {
                    const int co = (wc * 128 + j * 16 + ln) * 64
                                 + (((ks8 + quad) ^ sw) << 3);
                    const s16x8 bh = *(const s16x8*)(sBh + co);
                    const s16x8 bl = *(const s16x8*)(sBl + co);
#pragma unroll
                    for (int i = 0; i < 4; ++i) {
                        acc[i][j] = __builtin_amdgcn_mfma_f32_16x16x32_bf16(ahf[i], bh, acc[i][j], 0, 0, 0);
                        acc[i][j] = __builtin_amdgcn_mfma_f32_16x16x32_bf16(alf[i], bh, acc[i][j], 0, 0, 0);
                        acc[i][j] = __builtin_amdgcn_mfma_f32_16x16x32_bf16(ahf[i], bl, acc[i][j], 0, 0, 0);
                    }
                }
            }
        }

        // epilogue. C/D layout: col=lane&15, row=quad*4+reg (m89/m91-verified).
        if (st == 11) {
#pragma unroll
            for (int i = 0; i < 4; ++i)
#pragma unroll
                for (int j = 0; j < 8; ++j) {
                    const int col = wc * 128 + j * 16 + ln;
#pragma unroll
                    for (int r = 0; r < 4; ++r) {
                        const int row = wr * 64 + i * 16 + quad * 4 + r;
                        O[row * DD + col] = sqrtN * acc[i][j][r];
                    }
                }
        } else {
            short* Ch = Sl4[(int)sc_[st]];
            short* Cl = Ch + PLN;
            const int axs = ax_[st];
            const short* Wh = (axs >= 0) ? (const short*)Sl4[axs] : nullptr;
            const short* Wl = Wh ? Wh + PLN : nullptr;
            const float alpha = (axs >= 0) ? -0.5f : 1.0f;
#pragma unroll
            for (int i = 0; i < 4; ++i)
#pragma unroll
                for (int j = 0; j < 8; ++j) {
                    const int col = wc * 128 + j * 16 + ln;
#pragma unroll
                    for (int r = 0; r < 4; ++r) {
                        const int row = wr * 64 + i * 16 + quad * 4 + r;
                        const int id2 = row * DD + col;
                        float v = alpha * acc[i][j][r];
                        if (Wh) v = fmaf(1.5f, bf16tof(Wh[id2]) + bf16tof(Wl[id2]), v);
                        const short h = bf16rtn(v);
                        Ch[id2] = h;
                        Cl[id2] = bf16rtn(v - bf16tof(h));
                    }
                }
        }
        __threadfence();    // stores -> L2, invalidate L1 (same-block RAW)
        __syncthreads();
    }
}

extern "C" void kernel_launch(void* const* d_in, const int* in_sizes, int n_in,
                              void* d_out, int out_size, void* d_ws, size_t ws_size,
                              hipStream_t stream)
{
    const float* x = (const float*)d_in[0];
    float* out = (float*)d_out;
    const int NB = 256;

    // ws: nbuf elems x 3 slots x 2 planes; A planes live in d_out.
    short* base = (short*)d_ws;
    long availsh = (long)(ws_size / 2);
    int nbuf = (int)(availsh / (6L * PLN));
    if (nbuf > NB) nbuf = NB;
    if (nbuf < 1) nbuf = 1;

    for (int c0 = 0; c0 < NB; c0 += nbuf) {
        const int n = (NB - c0 < nbuf) ? (NB - c0) : nbuf;
        sqrtm_chain<<<dim3(n), dim3(512), 0, stream>>>(
            x + (size_t)c0 * MATN, out + (size_t)c0 * MATN, base);
    }
}

// Round 3
// 1352.229 us; speedup vs baseline: 1.9019x; 1.9019x over previous
//
#include <hip/hip_runtime.h>

// Persistent per-matrix Newton-Schulz sqrtm. B=256, D=256, iterN=5.
// Round 8: round-7 single-kernel structure with the two latency killers fixed:
//  (1) __threadfence() REMOVED. It compiled to agent-scope buffer_wbl2 +
//      buffer_inv sc1 (full per-XCD L2 writeback+invalidate) x 13 steps x 256
//      blocks -- the round-7 2472us disaster. It was never needed: all
//      accesses to a matrix are by ONE block on ONE CU, and same-CU
//      store->load through the write-through vector L1 is hardware-coherent;
//      cross-wave visibility needs only __syncthreads()'s vmcnt(0) drain.
//  (2) k-tile staging double-buffered (catalog T3 minimum 2-phase, m248v2):
//      BK=32, 2 x 64KB LDS buffers; STAGE(next) issued BEFORE compute(cur),
//      one __syncthreads() per tile. The barrier's lgkmcnt drain makes the
//      buffer overwrite WAR-safe.
//
// Storage: fp32 emulated as 2-term bf16 planes (hi+lo), product via 3 MFMA:
//   A@B ~= Ah@Bh + Al@Bh + Ah@Bl
// All iterates are symmetric polynomials in A => C = A@B^T == A@B, so both
// operands are read as [outer][k] rows (no transposition anywhere).
//
// LDS swizzle (rule #21, both-sides): physical 8-short slot s of row r holds
// global slot s ^ ((r>>1)&3); applied on the pre-swizzled GLOBAL source
// (linear global_load_lds dest) and the same XOR on the ds_read side.
//
// Chain (A planes live in d_out, dead before the final fp32 overwrite):
//   Z1 = 1.5I - 0.5A
//   3x:  W = A@Z ; T = 1.5W - 0.5(Z@W) ; Z' = T@Z
//   fin: W = A@Z ; T = 1.5W - 0.5(W@Z) ; out = sqrt(normA)*(T@W)

#define DD 256
#define PLN 65536   // shorts per bf16 plane
#define MATN 65536  // floats per fp32 matrix

typedef short s16x8 __attribute__((ext_vector_type(8)));
typedef short s16x4 __attribute__((ext_vector_type(4)));
typedef float f32x4 __attribute__((ext_vector_type(4)));

__device__ __forceinline__ short bf16rtn(float f) {
    unsigned u = __float_as_uint(f);
    u += 0x7FFFu + ((u >> 16) & 1u);   // round-to-nearest-even
    return (short)(u >> 16);
}
__device__ __forceinline__ float bf16tof(short h) {
    return __uint_as_float(((unsigned)(unsigned short)h) << 16);
}
__device__ __forceinline__ void gload16(const short* g, short* l) {
    __builtin_amdgcn_global_load_lds(
        (const __attribute__((address_space(1))) void*)g,
        (__attribute__((address_space(3))) void*)l, 16, 0, 0);
}

__global__ __launch_bounds__(512, 2) void sqrtm_chain(
    const float* __restrict__ x, float* __restrict__ out,
    short* __restrict__ ws)
{
    // 4 arrays x (2 buffers x 8192 shorts) = 128 KiB
    __shared__ __align__(16) short sAh[16384];
    __shared__ __align__(16) short sAl[16384];
    __shared__ __align__(16) short sBh[16384];
    __shared__ __align__(16) short sBl[16384];
    __shared__ float red[8];
    __shared__ float sSc[2];

    const int lb = blockIdx.x, tid = threadIdx.x;
    const int wave = tid >> 6, lane = tid & 63;
    const int ln = lane & 15, quad = lane >> 4;
    const int wr = wave & 3, wc = wave >> 2;   // wave tile: rows wr*64, cols wc*128
    const int sw = (ln >> 1) & 3;              // read-side swizzle key

    const float* X = x + (size_t)lb * MATN;
    float* O = out + (size_t)lb * MATN;
    short* Xpl = (short*)O;                    // A planes live in out region
    short* S0 = ws + (size_t)lb * (6 * (size_t)PLN);
    short* S1 = S0 + 2 * PLN;
    short* S2 = S0 + 4 * PLN;

    // ---------------- setup: normA, A planes, Z1 planes ----------------
    {
        float s = 0.f;
#pragma unroll
        for (int i = 0; i < 32; ++i) {
            const float4 v = *(const float4*)(X + ((i * 512 + tid) << 2));
            s += v.x + v.y + v.z + v.w;
        }
#pragma unroll
        for (int o = 32; o; o >>= 1) s += __shfl_down(s, o, 64);
        if (lane == 0) red[wave] = s;
        __syncthreads();
        if (tid == 0) {
            float t = 0.f;
#pragma unroll
            for (int i = 0; i < 8; ++i) t += red[i];
            sSc[0] = 1.f / t;
            sSc[1] = sqrtf(t);
        }
        __syncthreads();
    }
    const float invN = sSc[0];
    const float sqrtN = sSc[1];
    {
        short* Xh = Xpl;  short* Xl = Xpl + PLN;
        short* Zh = S0;   short* Zl = S0 + PLN;
#pragma unroll 4
        for (int i = 0; i < 32; ++i) {
            const int e = (i * 512 + tid) << 2;
            const int r = e >> 8, c = e & 255;
            const float4 v = *(const float4*)(X + e);
            const float a0 = invN * v.x, a1 = invN * v.y,
                        a2 = invN * v.z, a3 = invN * v.w;
            s16x4 xh, xl, zh, zl;
            xh[0] = bf16rtn(a0); xl[0] = bf16rtn(a0 - bf16tof(xh[0]));
            xh[1] = bf16rtn(a1); xl[1] = bf16rtn(a1 - bf16tof(xh[1]));
            xh[2] = bf16rtn(a2); xl[2] = bf16rtn(a2 - bf16tof(xh[2]));
            xh[3] = bf16rtn(a3); xl[3] = bf16rtn(a3 - bf16tof(xh[3]));
            const float z0 = ((r == c + 0) ? 1.5f : 0.f) - 0.5f * a0;
            const float z1 = ((r == c + 1) ? 1.5f : 0.f) - 0.5f * a1;
            const float z2 = ((r == c + 2) ? 1.5f : 0.f) - 0.5f * a2;
            const float z3 = ((r == c + 3) ? 1.5f : 0.f) - 0.5f * a3;
            zh[0] = bf16rtn(z0); zl[0] = bf16rtn(z0 - bf16tof(zh[0]));
            zh[1] = bf16rtn(z1); zl[1] = bf16rtn(z1 - bf16tof(zh[1]));
            zh[2] = bf16rtn(z2); zl[2] = bf16rtn(z2 - bf16tof(zh[2]));
            zh[3] = bf16rtn(z3); zl[3] = bf16rtn(z3 - bf16tof(zh[3]));
            *(s16x4*)(Xh + e) = xh; *(s16x4*)(Xl + e) = xl;
            *(s16x4*)(Zh + e) = zh; *(s16x4*)(Zl + e) = zl;
        }
    }
    __syncthreads();   // setup stores drained (vmcnt0); same-CU L1 coherent

    // staging coords (fixed per thread): wave pair (2w,2w+1) -> array w;
    // 128 threads/array, 4 threads (16B each) per 32-short row.
    const int arr = tid >> 7;
    const int idx = tid & 127;
    const int r0 = idx >> 2;                   // 0..31
    const int slot = idx & 3;                  // 0..3
    const int gs = slot ^ ((r0 >> 1) & 3);     // pre-swizzled source slot
    short* lbase = (arr == 0) ? sAh : (arr == 1) ? sAl : (arr == 2) ? sBh : sBl;
    short* const myl = lbase + (wave & 1) * 512;   // wave-uniform LDS dest
    const int goff = r0 * DD + gs * 8;

    // step tables: operand/dest slot ids (0,1,2 = ws slots; 3 = A planes)
    const signed char sa_[12] = {3,0,2, 3,1,2, 3,0,2, 3,0,2};
    const signed char sb_[12] = {0,1,0, 1,0,1, 0,1,0, 1,1,0};
    const signed char sc_[12] = {1,2,1, 0,2,0, 1,2,1, 0,2,0};   // sc_[11] unused
    const signed char ax_[12] = {-1,1,-1, -1,0,-1, -1,1,-1, -1,0,-1};
    short* Sl4[4] = {S0, S1, S2, Xpl};

#pragma unroll 1
    for (int st = 0; st < 12; ++st) {
        const short* Ap = Sl4[(int)sa_[st]];
        const short* Bp = Sl4[(int)sb_[st]];
        const short* gsrc = ((arr < 2) ? Ap : Bp) + (arr & 1) * PLN + goff;

        f32x4 acc[4][8];
#pragma unroll
        for (int i = 0; i < 4; ++i)
#pragma unroll
            for (int j = 0; j < 8; ++j) {
                acc[i][j][0] = 0.f; acc[i][j][1] = 0.f;
                acc[i][j][2] = 0.f; acc[i][j][3] = 0.f;
            }

        // prologue: stage k-tile 0 into buf 0 (full drain -- once per step)
#pragma unroll
        for (int rr = 0; rr < 8; ++rr)
            gload16(gsrc + rr * (32 * DD), myl + rr * 1024);
        __syncthreads();

        int cur = 0;
#pragma unroll 2
        for (int t = 0; t < 8; ++t) {
            if (t < 7) {   // issue next tile's stage BEFORE compute
                const short* g2 = gsrc + (t + 1) * 32;
                short* l2 = myl + ((cur ^ 1) << 13);
#pragma unroll
                for (int rr = 0; rr < 8; ++rr)
                    gload16(g2 + rr * (32 * DD), l2 + rr * 1024);
            }
            // compute k-tile cur (96 MFMA/wave) while next stage flies
            const int bo = cur << 13;
            s16x8 ahf[4], alf[4];
#pragma unroll
            for (int i = 0; i < 4; ++i) {
                const int ro = bo + (wr * 64 + i * 16 + ln) * 32
                             + ((quad ^ sw) << 3);
                ahf[i] = *(const s16x8*)(sAh + ro);
                alf[i] = *(const s16x8*)(sAl + ro);
            }
#pragma unroll
            for (int j = 0; j < 8; ++j) {
                const int co = bo + (wc * 128 + j * 16 + ln) * 32
                             + ((quad ^ sw) << 3);
                const s16x8 bh = *(const s16x8*)(sBh + co);
                const s16x8 bl = *(const s16x8*)(sBl + co);
#pragma unroll
                for (int i = 0; i < 4; ++i) {
                    acc[i][j] = __builtin_amdgcn_mfma_f32_16x16x32_bf16(ahf[i], bh, acc[i][j], 0, 0, 0);
                    acc[i][j] = __builtin_amdgcn_mfma_f32_16x16x32_bf16(alf[i], bh, acc[i][j], 0, 0, 0);
                    acc[i][j] = __builtin_amdgcn_mfma_f32_16x16x32_bf16(ahf[i], bl, acc[i][j], 0, 0, 0);
                }
            }
            __syncthreads();   // drains stage (vmcnt0) + my ds_reads (lgkm)
            cur ^= 1;
        }

        // epilogue. C/D layout: col=lane&15, row=quad*4+reg (m89/m91-verified).
        if (st == 11) {
#pragma unroll
            for (int i = 0; i < 4; ++i)
#pragma unroll
                for (int j = 0; j < 8; ++j) {
                    const int col = wc * 128 + j * 16 + ln;
#pragma unroll
                    for (int r = 0; r < 4; ++r) {
                        const int row = wr * 64 + i * 16 + quad * 4 + r;
                        O[row * DD + col] = sqrtN * acc[i][j][r];
                    }
                }
        } else {
            short* Ch = Sl4[(int)sc_[st]];
            short* Cl = Ch + PLN;
            const int axs = ax_[st];
            const short* Wh = (axs >= 0) ? (const short*)Sl4[axs] : nullptr;
            const short* Wl = Wh ? Wh + PLN : nullptr;
            const float alpha = (axs >= 0) ? -0.5f : 1.0f;
#pragma unroll
            for (int i = 0; i < 4; ++i)
#pragma unroll
                for (int j = 0; j < 8; ++j) {
                    const int col = wc * 128 + j * 16 + ln;
#pragma unroll
                    for (int r = 0; r < 4; ++r) {
                        const int row = wr * 64 + i * 16 + quad * 4 + r;
                        const int id2 = row * DD + col;
                        float v = alpha * acc[i][j][r];
                        if (Wh) v = fmaf(1.5f, bf16tof(Wh[id2]) + bf16tof(Wl[id2]), v);
                        const short h = bf16rtn(v);
                        Ch[id2] = h;
                        Cl[id2] = bf16rtn(v - bf16tof(h));
                    }
                }
            __syncthreads();   // stores drained before next step's stage reads
        }
    }
}

extern "C" void kernel_launch(void* const* d_in, const int* in_sizes, int n_in,
                              void* d_out, int out_size, void* d_ws, size_t ws_size,
                              hipStream_t stream)
{
    const float* x = (const float*)d_in[0];
    float* out = (float*)d_out;
    const int NB = 256;

    // ws: nbuf elems x 3 slots x 2 planes; A planes live in d_out.
    short* base = (short*)d_ws;
    long availsh = (long)(ws_size / 2);
    int nbuf = (int)(availsh / (6L * PLN));
    if (nbuf > NB) nbuf = NB;
    if (nbuf < 1) nbuf = 1;

    for (int c0 = 0; c0 < NB; c0 += nbuf) {
        const int n = (NB - c0 < nbuf) ? (NB - c0) : nbuf;
        sqrtm_chain<<<dim3(n), dim3(512), 0, stream>>>(
            x + (size_t)c0 * MATN, out + (size_t)c0 * MATN, base);
    }
}